// Round 7
// baseline (248.020 us; speedup 1.0000x reference)
//
#include <hip/hip_runtime.h>
#include <cfloat>
#include <math.h>

// Exact-replication KNN (k=10, +self) + rank-column gather max-pool.
// NUMERICS FROZEN (R3 pass, absmax 0.0): fp32 chains
//   sq  = fma(z,z, fma(y,y, rn(x*x)))
//   dot = fma(z,z', fma(y,y', rn(x*x')))
//   d   = fma(dot, -2, rn(sq_i+sq_j))    [== rn(sum - rn(2*dot)), 2*dot exact]
// Selection order = jax top_k = ascending lexicographic (d, orig_idx) —
// proven order-independent in R8/R9 (absmax 0.0, nondeterministic scatter).
//
// Round 17: dispatch-overhead fusion. Wall - knn has been ~75 us constant
// across R10-R16 regardless of prepass structure; the prepass kernels sum
// to ~15 us, so ~60 us is per-dispatch overhead (~10 us x 6) + bubbles.
// Fuse hist+scan+scatter+aabb into ONE 128-block kernel with a hand-rolled
// device-scope grid barrier (monotonic counter, zeroed by the same
// hipMemsetAsync as hist; device atomics + __threadfence release/acquire
// per Guideline 16; 128 blocks <= 256 CUs -> all resident, no deadlock).
// Scatter reuses hist-phase registers (coords+cell cached). 6 -> 3
// dispatches. knn_pool_kernel byte-identical to R16 (4-slot ring, radix
// init, zigzag + live recheck).

#define N_PTS    16384
#define C_FEAT   64
#define KK       11
#define NCELLS   4096                 // 16^3 Morton cells
#define TILE     128                  // sorted points per tile
#define NTILES   (N_PTS / TILE)       // 128
#define WQ       4
#define NWAVES   4
#define NTHREADS (NWAVES * 64)
#define QPB      (NWAVES * WQ)        // 16 queries per block
#define GRID_PRE 128                  // prepass blocks (all co-resident)

// d_ws layout (bytes)
#define WS_CAND  0                            // float4[2][N_PTS]   512 KB
#define WS_AABB  (WS_CAND + 2*N_PTS*16)       // float[2][NTILES][6]  6 KB
#define WS_HIST  (WS_AABB + 2*NTILES*6*4)     // int[2][NCELLS]      32 KB
#define WS_BAR   (WS_HIST + 2*NCELLS*4)       // int[4] grid barriers

__device__ __forceinline__ int cell_of(float x, float y, float z) {
    int cx = (int)floorf((x + 4.5f) * (16.0f / 9.0f));
    int cy = (int)floorf((y + 4.5f) * (16.0f / 9.0f));
    int cz = (int)floorf((z + 4.5f) * (16.0f / 9.0f));
    cx = min(15, max(0, cx));
    cy = min(15, max(0, cy));
    cz = min(15, max(0, cz));
    int m = 0;
    #pragma unroll
    for (int b = 0; b < 4; ++b)
        m |= (((cx >> b) & 1) << (3 * b)) |
             (((cy >> b) & 1) << (3 * b + 1)) |
             (((cz >> b) & 1) << (3 * b + 2));
    return m;
}

// Device-scope grid barrier. Monotonic counter (one int per barrier site,
// zeroed each iteration by the memsetAsync). Release: __threadfence (sc1
// L2 writeback on gfx950) before arrive; acquire: __threadfence after.
__device__ __forceinline__ void gbar(int* bar) {
    __syncthreads();
    __threadfence();
    if (threadIdx.x == 0) {
        const int old = atomicAdd(bar, 1);
        const int target = (old / GRID_PRE + 1) * GRID_PRE;
        while (atomicAdd(bar, 0) < target) {}
    }
    __syncthreads();
    __threadfence();
}

// Fused prepass: hist -> scan -> scatter -> aabb. 128 blocks x 256 thr.
// hist pre-zeroed by hipMemsetAsync (which also zeroes the barrier ints).
__global__ __launch_bounds__(256) void prepass_kernel(
    const float* __restrict__ src_c, const float* __restrict__ tgt_c,
    int* __restrict__ hist, int* __restrict__ bar,
    float4* __restrict__ cand, float* __restrict__ aabb)
{
    const int tid = threadIdx.x;
    const int inst = blockIdx.x >> 6;           // 64 blocks per instance
    const float* __restrict__ coords = inst ? tgt_c : src_c;
    int* __restrict__ h = hist + inst * NCELLS;
    float4* __restrict__ cb = cand + inst * N_PTS;

    __shared__ int sd[256];

    // ---- Phase A: histogram (one point per thread; cache for scatter) ----
    const int p = ((blockIdx.x & 63) << 8) + tid;
    const float x = coords[3 * p], y = coords[3 * p + 1], z = coords[3 * p + 2];
    const int cell = cell_of(x, y, z);
    atomicAdd(&h[cell], 1);
    gbar(&bar[0]);

    // ---- Phase B: exclusive scan (blocks 0,1; 16 cells/thread) ----
    if (blockIdx.x < 2) {
        int* __restrict__ hh = hist + blockIdx.x * NCELLS;
        int v[16], ssum = 0;
        #pragma unroll
        for (int j = 0; j < 16; ++j) { v[j] = hh[tid * 16 + j]; ssum += v[j]; }
        sd[tid] = ssum;
        __syncthreads();
        for (int off = 1; off < 256; off <<= 1) {
            const int xx = (tid >= off) ? sd[tid - off] : 0;
            __syncthreads();
            sd[tid] += xx;
            __syncthreads();
        }
        int base = sd[tid] - ssum;
        #pragma unroll
        for (int j = 0; j < 16; ++j) { hh[tid * 16 + j] = base; base += v[j]; }
    }
    gbar(&bar[1]);

    // ---- Phase C: scatter (same thread -> same point; regs cached) ----
    // Within-cell order nondeterministic — exactly as R8-R16 (selection
    // proven order-independent).
    const int dst = atomicAdd(&h[cell], 1);
    cb[dst] = make_float4(x, y, z, __int_as_float(p));
    gbar(&bar[2]);

    // ---- Phase D: AABB (wave w handles tile w; 256 tiles, 512 waves) ----
    const int w = blockIdx.x * 4 + (tid >> 6);
    if (w < 2 * NTILES) {
        const int base = (w / NTILES) * N_PTS + (w % NTILES) * TILE;
        const int lane = tid & 63;
        float4 a = cand[base + lane], b = cand[base + 64 + lane];
        float mnx = fminf(a.x, b.x), mny = fminf(a.y, b.y), mnz = fminf(a.z, b.z);
        float mxx = fmaxf(a.x, b.x), mxy = fmaxf(a.y, b.y), mxz = fmaxf(a.z, b.z);
        #pragma unroll
        for (int off = 1; off < 64; off <<= 1) {
            mnx = fminf(mnx, __shfl_xor(mnx, off));
            mny = fminf(mny, __shfl_xor(mny, off));
            mnz = fminf(mnz, __shfl_xor(mnz, off));
            mxx = fmaxf(mxx, __shfl_xor(mxx, off));
            mxy = fmaxf(mxy, __shfl_xor(mxy, off));
            mxz = fmaxf(mxz, __shfl_xor(mxz, off));
        }
        if (lane == 0) {
            aabb[w * 6 + 0] = mnx; aabb[w * 6 + 1] = mny; aabb[w * 6 + 2] = mnz;
            aabb[w * 6 + 3] = mxx; aabb[w * 6 + 4] = mxy; aabb[w * 6 + 5] = mxz;
        }
    }
}

// Frozen distance chain for candidate C vs query q (do not reorder).
#define DIST_TO(C, q, dout)                                                 \
  { const float csq_ = __fmaf_rn((C).z, (C).z, __fmaf_rn((C).y, (C).y,      \
                                 __fmul_rn((C).x, (C).x)));                 \
    float dot_ = __fmul_rn((C).x, qx[q]);                                   \
    dot_ = __fmaf_rn((C).y, qy[q], dot_);                                   \
    dot_ = __fmaf_rn((C).z, qz[q], dot_);                                   \
    (dout) = __fmaf_rn(dot_, -2.0f, __fadd_rn(qsq[q], csq_)); }

// One 64-candidate batch vs the wave's 4 queries (proven in R8/R9).
#define PROCESS_BATCH(C)                                                    \
  {                                                                         \
    const float cx = (C).x, cy = (C).y, cz = (C).z;                         \
    const int corig = __float_as_int((C).w);                                \
    const float csq = __fmaf_rn(cz, cz, __fmaf_rn(cy, cy,                   \
                                __fmul_rn(cx, cx)));                        \
    _Pragma("unroll")                                                       \
    for (int q = 0; q < WQ; ++q) {                                          \
      float dot = __fmul_rn(cx, qx[q]);                                     \
      dot = __fmaf_rn(cy, qy[q], dot);                                      \
      dot = __fmaf_rn(cz, qz[q], dot);                                      \
      const float sum = __fadd_rn(qsq[q], csq);                             \
      const float d = __fmaf_rn(dot, -2.0f, sum);                           \
      unsigned long long m = __ballot(d <= worst[q]);                       \
      while (m) {                                                           \
        const int sl = (int)__builtin_ctzll(m);                             \
        m &= m - 1;                                                         \
        const float nd = __int_as_float(__builtin_amdgcn_readlane(          \
            __float_as_int(d), sl));                                        \
        if (nd <= worst[q]) {                                               \
          const int norig = __builtin_amdgcn_readlane(corig, sl);           \
          const float pld = __int_as_float(                                 \
              __builtin_amdgcn_ds_bpermute(upaddr, __float_as_int(ld)));    \
          const int pli = __builtin_amdgcn_ds_bpermute(upaddr, li);         \
          const bool gt = (ld > nd) || (ld == nd && li > norig);            \
          if (ingrp[q] && gt) {                                             \
            const bool pgt = (pld > nd) || (pld == nd && pli > norig);      \
            const bool fst = (lrank == 0) || (!pgt);                        \
            ld = fst ? nd : pld;                                            \
            li = fst ? norig : pli;                                         \
          }                                                                 \
          worst[q] = fminf(worst[q],                                        \
              __int_as_float(__builtin_amdgcn_readlane(                     \
                  __float_as_int(ld), q * 16 + (KK - 1))));                 \
        }                                                                   \
      }                                                                     \
    }                                                                       \
  }

#define WMAX4 fmaxf(fmaxf(worst[0], worst[1]), fmaxf(worst[2], worst[3]))

__global__ __launch_bounds__(NTHREADS) void knn_pool_kernel(
    const float* __restrict__ src_f, const float* __restrict__ tgt_f,
    const float4* __restrict__ cand, const float* __restrict__ aabb,
    float* __restrict__ out)
{
    const int inst = blockIdx.x & 1;
    const float* __restrict__ feats = inst ? tgt_f : src_f;
    float* __restrict__ outb = out + (size_t)inst * N_PTS * (2 * C_FEAT);
    const float4* __restrict__ cd = cand + inst * N_PTS;

    const int tid = threadIdx.x, wave = tid >> 6, lane = tid & 63;
    const int lq = lane >> 4, lrank = lane & 15;
    const bool inlist = (lrank < KK);
    const int upaddr = ((lane + 63) & 63) << 2;   // ds_bpermute: lane-1

    __shared__ float sab[NTILES * 6];                 // 3 KB
    __shared__ unsigned int slist[NWAVES][NTILES];    // packed (lb|tile), 2 KB
    for (int i = tid; i < NTILES * 6; i += NTHREADS)
        sab[i] = aabb[inst * NTILES * 6 + i];
    __syncthreads();

    const int q0 = (blockIdx.x >> 1) * QPB + wave * WQ;  // sorted row
    float qx[WQ], qy[WQ], qz[WQ], qsq[WQ];
    int qor[WQ]; bool ingrp[WQ]; float worst[WQ];
    float wqmnx = FLT_MAX, wqmny = FLT_MAX, wqmnz = FLT_MAX;
    float wqmxx = -FLT_MAX, wqmxy = -FLT_MAX, wqmxz = -FLT_MAX;
    #pragma unroll
    for (int q = 0; q < WQ; ++q) {
        const float4 c = cd[q0 + q];
        qx[q] = c.x; qy[q] = c.y; qz[q] = c.z;
        qor[q] = __float_as_int(c.w);
        qsq[q] = __fmaf_rn(c.z, c.z, __fmaf_rn(c.y, c.y, __fmul_rn(c.x, c.x)));
        ingrp[q] = inlist && (lq == q);
        worst[q] = FLT_MAX;
        wqmnx = fminf(wqmnx, c.x); wqmxx = fmaxf(wqmxx, c.x);
        wqmny = fminf(wqmny, c.y); wqmxy = fmaxf(wqmxy, c.y);
        wqmnz = fminf(wqmnz, c.z); wqmxz = fmaxf(wqmxz, c.z);
    }

    float ld = FLT_MAX;   // lane-distributed sorted list (lex (d, orig_idx))
    int   li = 0x7fffffff;

    const int ownt = q0 / TILE;   // tile containing the queries

    // ---- own tile: radix-select exact 11th distance -> tight worst init --
    {
        const float4 c0 = cd[ownt * TILE + lane];
        const float4 c1 = cd[ownt * TILE + 64 + lane];

        // Order-preserving uint keys of the frozen fp32 distances
        // (bijective; handles the -eps self-distance sign case).
        unsigned k0[WQ], k1[WQ], pk[WQ];
        #pragma unroll
        for (int q = 0; q < WQ; ++q) {
            float d0, d1;
            DIST_TO(c0, q, d0);
            DIST_TO(c1, q, d1);
            const unsigned b0 = __float_as_uint(d0), b1 = __float_as_uint(d1);
            k0[q] = b0 ^ (((unsigned)((int)b0 >> 31)) | 0x80000000u);
            k1[q] = b1 ^ (((unsigned)((int)b1 >> 31)) | 0x80000000u);
            pk[q] = 0u;
        }
        // MSB->LSB bisection: after the loop pk[q] == key of the exact
        // 11th-smallest (counting multiplicity) of the 128 own-tile dists.
        for (int b = 31; b >= 0; --b) {
            #pragma unroll
            for (int q = 0; q < WQ; ++q) {
                const unsigned mid = pk[q] | (1u << b);
                const int cnt = (int)__popcll(__ballot(k0[q] < mid))
                              + (int)__popcll(__ballot(k1[q] < mid));
                if (cnt < KK) pk[q] = mid;
            }
        }
        #pragma unroll
        for (int q = 0; q < WQ; ++q) {
            const unsigned p = pk[q];
            worst[q] = __uint_as_float(
                (p & 0x80000000u) ? (p ^ 0x80000000u) : ~p);
        }
        // Gated batches: m now has ~11+ties bits total; the serial insert
        // (unchanged logic) rebuilds the exact lex-sorted list.
        PROCESS_BATCH(c0);
        PROCESS_BATCH(c1);
    }
    const float wmax0 = WMAX4;

    // ---- zigzag (near->far) survivor list, built in parallel ----
    // entry = (float_bits(lb) & ~0xFF) | tile  — lb>=0 so uint order == lb
    // order; unpacked lb rounds DOWN => recheck skip stays conservative.
    int nsurv = 0;
    #pragma unroll
    for (int g = 0; g < 4; ++g) {
        const int p = g * 64 + lane;
        const int o = (p >> 1) + 1;
        const int t = (p & 1) ? (ownt - o) : (ownt + o);
        bool ok = (t >= 0) && (t < NTILES);
        float lb = 0.0f;
        if (ok) {
            const float dx = fmaxf(0.f, fmaxf(sab[t*6+0] - wqmxx, wqmnx - sab[t*6+3]));
            const float dy = fmaxf(0.f, fmaxf(sab[t*6+1] - wqmxy, wqmny - sab[t*6+4]));
            const float dz = fmaxf(0.f, fmaxf(sab[t*6+2] - wqmxz, wqmnz - sab[t*6+5]));
            lb = dx * dx;
            lb = fmaf(dy, dy, lb);
            lb = fmaf(dz, dz, lb);
            ok = (lb - 1e-3f) <= wmax0;   // margin >> fp32 chain error
        }
        const unsigned long long mk = __ballot(ok);
        if (ok) {
            const int idx = nsurv + (int)__popcll(mk & ((1ull << lane) - 1ull));
            slist[wave][idx] = (__float_as_uint(lb) & 0xFFFFFF00u) | (unsigned)t;
        }
        nsurv += (int)__popcll(mk);
    }

    // ---- scan survivors: 4-slot prefetch ring + LIVE recheck vs wmax ----
    // Loads for slot s issue while slot s-4 is processed (~3 tiles of
    // latency cover for the occupancy-decayed tail regime). Tail slots
    // prefetch ownt harmlessly (never processed: loop bound).
    float4 T0a, T0b, T1a, T1b, T2a, T2b, T3a, T3b;
    unsigned int u0 = 0, u1 = 0, u2 = 0, u3 = 0;
    {
        u0 = (0 < nsurv) ? slist[wave][0] : (unsigned)ownt;
        const int t0 = (int)(u0 & 0xFFu);
        T0a = cd[t0 * TILE + lane]; T0b = cd[t0 * TILE + 64 + lane];
        u1 = (1 < nsurv) ? slist[wave][1] : (unsigned)ownt;
        const int t1 = (int)(u1 & 0xFFu);
        T1a = cd[t1 * TILE + lane]; T1b = cd[t1 * TILE + 64 + lane];
        u2 = (2 < nsurv) ? slist[wave][2] : (unsigned)ownt;
        const int t2 = (int)(u2 & 0xFFu);
        T2a = cd[t2 * TILE + lane]; T2b = cd[t2 * TILE + 64 + lane];
        u3 = (3 < nsurv) ? slist[wave][3] : (unsigned)ownt;
        const int t3 = (int)(u3 & 0xFFu);
        T3a = cd[t3 * TILE + lane]; T3b = cd[t3 * TILE + 64 + lane];
    }
    #define SCAN_STEP(UA, TA, TB)                                           \
      {                                                                     \
        const unsigned uN = (s + 4 < nsurv) ? slist[wave][s + 4]            \
                                            : (unsigned)ownt;               \
        const int tn = (int)(uN & 0xFFu);                                   \
        if (__uint_as_float(UA & 0xFFFFFF00u) - 1e-3f <= WMAX4) {           \
            PROCESS_BATCH(TA);                                              \
            PROCESS_BATCH(TB);                                              \
        }                                                                   \
        UA = uN;                                                            \
        TA = cd[tn * TILE + lane]; TB = cd[tn * TILE + 64 + lane];          \
        ++s;                                                                \
      }
    int s = 0;
    while (s < nsurv) {
        SCAN_STEP(u0, T0a, T0b);
        if (s >= nsurv) break;
        SCAN_STEP(u1, T1a, T1b);
        if (s >= nsurv) break;
        SCAN_STEP(u2, T2a, T2b);
        if (s >= nsurv) break;
        SCAN_STEP(u3, T3a, T3b);
    }
    #undef SCAN_STEP

    // Rank 0 (lex-smallest: self or -1ulp near-twin) dropped positionally.
    // Ranks 1..10 -> feature columns 0..9. li holds ORIGINAL indices.
    float fv = -FLT_MAX;
    if (inlist && lrank >= 1)
        fv = feats[(size_t)li * C_FEAT + (lrank - 1)];
    #pragma unroll
    for (int off = 1; off < 16; off <<= 1)
        fv = fmaxf(fv, __shfl_xor(fv, off));

    #pragma unroll
    for (int q = 0; q < WQ; ++q) {
        const float M   = __shfl(fv, q * 16);
        const int   row = qor[q];
        const float v   = feats[(size_t)row * C_FEAT + lane];
        outb[(size_t)row * (2 * C_FEAT) + lane]          = v;
        outb[(size_t)row * (2 * C_FEAT) + C_FEAT + lane] = M - v;
    }
}

extern "C" void kernel_launch(void* const* d_in, const int* in_sizes, int n_in,
                              void* d_out, int out_size, void* d_ws, size_t ws_size,
                              hipStream_t stream) {
    const float* src_f = (const float*)d_in[0];
    const float* tgt_f = (const float*)d_in[1];
    const float* src_c = (const float*)d_in[2];
    const float* tgt_c = (const float*)d_in[3];
    float* out = (float*)d_out;

    char* ws = (char*)d_ws;
    float4* cand = (float4*)(ws + WS_CAND);
    float*  aabb = (float*) (ws + WS_AABB);
    int*    hist = (int*)   (ws + WS_HIST);
    int*    bar  = (int*)   (ws + WS_BAR);

    // Zero hist (32 KB) + barrier counters (16 B) in one memset.
    hipMemsetAsync(hist, 0, 2 * NCELLS * sizeof(int) + 4 * sizeof(int), stream);
    hipLaunchKernelGGL(prepass_kernel, dim3(GRID_PRE), dim3(256), 0, stream,
                       src_c, tgt_c, hist, bar, cand, aabb);
    hipLaunchKernelGGL(knn_pool_kernel, dim3(2 * (N_PTS / QPB)), dim3(NTHREADS),
                       0, stream, src_f, tgt_f, cand, aabb, out);
}

// Round 8
// 220.441 us; speedup vs baseline: 1.1251x; 1.1251x over previous
//
#include <hip/hip_runtime.h>
#include <cfloat>
#include <math.h>

// Exact-replication KNN (k=10, +self) + rank-column gather max-pool.
// NUMERICS FROZEN (R3 pass, absmax 0.0): fp32 chains
//   sq  = fma(z,z, fma(y,y, rn(x*x)))
//   dot = fma(z,z', fma(y,y', rn(x*x')))
//   d   = fma(dot, -2, rn(sq_i+sq_j))    [== rn(sum - rn(2*dot)), 2*dot exact]
// Selection order = jax top_k = ascending lexicographic (d, orig_idx) —
// proven order-independent in R8/R9 (absmax 0.0, nondeterministic scatter).
//
// Round 18: R17 post-mortem — fused prepass with spin grid-barriers
// REGRESSED (248 us): cross-XCD atomic polling costs more than the launch
// gaps it saves, and 126 blocks idled through the 2-block scan phase.
// Reverted. This round cuts dispatches 6 -> 4 with NO barriers, using only
// kernel-boundary ordering:
//   - scan fused into scatter: all 128 scatter blocks redundantly recompute
//     the 4096-cell exclusive scan in LDS (2 us, parallel), then scatter via
//     dst = lbase[cell] + atomicAdd(wptr[cell]) on a memset-zeroed wptr.
//   - AABB fused into scatter via monotone-key atomics: min tracked as
//     max(~keyf(v)), max as max(keyf(v)), both init 0 (same memset). Exact
//     same float min/max as the old shuffle reduction (no arithmetic).
// knn_pool_kernel identical to R16 except sab staging unkeys the AABB.

#define N_PTS    16384
#define C_FEAT   64
#define KK       11
#define NCELLS   4096                 // 16^3 Morton cells
#define TILE     128                  // sorted points per tile
#define NTILES   (N_PTS / TILE)       // 128
#define WQ       4
#define NWAVES   4
#define NTHREADS (NWAVES * 64)
#define QPB      (NWAVES * WQ)        // 16 queries per block

// d_ws layout (bytes)
#define WS_CAND  0                              // float4[2][N_PTS]   512 KB
#define WS_AABBU (WS_CAND + 2*N_PTS*16)         // uint[2][NTILES][6]  6 KB
#define WS_HIST  (WS_AABBU + 2*NTILES*6*4)      // int[2][NCELLS]     32 KB
#define WS_WPTR  (WS_HIST + 2*NCELLS*4)         // int[2][NCELLS]     32 KB
#define WS_ZERO_BYTES (2*NTILES*6*4 + 2*NCELLS*4 + 2*NCELLS*4)

__device__ __forceinline__ int cell_of(float x, float y, float z) {
    int cx = (int)floorf((x + 4.5f) * (16.0f / 9.0f));
    int cy = (int)floorf((y + 4.5f) * (16.0f / 9.0f));
    int cz = (int)floorf((z + 4.5f) * (16.0f / 9.0f));
    cx = min(15, max(0, cx));
    cy = min(15, max(0, cy));
    cz = min(15, max(0, cz));
    int m = 0;
    #pragma unroll
    for (int b = 0; b < 4; ++b)
        m |= (((cx >> b) & 1) << (3 * b)) |
             (((cy >> b) & 1) << (3 * b + 1)) |
             (((cz >> b) & 1) << (3 * b + 2));
    return m;
}

// Monotone (order-preserving, bijective) float<->uint key.
__device__ __forceinline__ unsigned keyf(float f) {
    const unsigned u = __float_as_uint(f);
    return (u & 0x80000000u) ? ~u : (u | 0x80000000u);
}
__device__ __forceinline__ float unkeyf(unsigned k) {
    return __uint_as_float((k & 0x80000000u) ? (k ^ 0x80000000u) : ~k);
}

// 128 blocks x 256 thr, one point per thread. Global atomics into hist
// (pre-zeroed by hipMemsetAsync).
__global__ __launch_bounds__(256) void hist_kernel(
    const float* __restrict__ src_c, const float* __restrict__ tgt_c,
    int* __restrict__ hist)
{
    const int inst = blockIdx.x >> 6;           // 64 blocks per instance
    const float* __restrict__ coords = inst ? tgt_c : src_c;
    int* __restrict__ h = hist + inst * NCELLS;
    const int p = ((blockIdx.x & 63) << 8) + threadIdx.x;
    const float* c = coords + (size_t)p * 3;
    atomicAdd(&h[cell_of(c[0], c[1], c[2])], 1);
}

// 128 blocks x 256 thr. Each block redundantly recomputes the exclusive
// scan of its instance's 4096-cell hist in LDS (parallel redundancy, ~2us),
// then scatters its 256 points: dst = lbase[cell] + atomicAdd(wptr[cell]).
// Within-cell order nondeterministic — as R8-R16 (order-independent).
// AABB per tile via monotone-key atomicMax (exact same floats as reduction).
__global__ __launch_bounds__(256) void scanscatter_kernel(
    const float* __restrict__ src_c, const float* __restrict__ tgt_c,
    const int* __restrict__ hist, int* __restrict__ wptr,
    unsigned* __restrict__ aabbu, float4* __restrict__ cand)
{
    const int tid = threadIdx.x;
    const int inst = blockIdx.x >> 6;
    const float* __restrict__ coords = inst ? tgt_c : src_c;
    const int* __restrict__ h = hist + inst * NCELLS;
    int* __restrict__ wp = wptr + inst * NCELLS;
    unsigned* __restrict__ au = aabbu + inst * NTILES * 6;
    float4* __restrict__ cb = cand + inst * N_PTS;

    __shared__ int sd[256];
    __shared__ int lbase[NCELLS];   // 16 KB

    int v[16], ssum = 0;
    #pragma unroll
    for (int j = 0; j < 16; ++j) { v[j] = h[tid * 16 + j]; ssum += v[j]; }
    sd[tid] = ssum;
    __syncthreads();
    for (int off = 1; off < 256; off <<= 1) {
        const int xx = (tid >= off) ? sd[tid - off] : 0;
        __syncthreads();
        sd[tid] += xx;
        __syncthreads();
    }
    int base = sd[tid] - ssum;
    #pragma unroll
    for (int j = 0; j < 16; ++j) { lbase[tid * 16 + j] = base; base += v[j]; }
    __syncthreads();

    const int p = ((blockIdx.x & 63) << 8) + tid;
    const float x = coords[3 * p], y = coords[3 * p + 1], z = coords[3 * p + 2];
    const int cell = cell_of(x, y, z);
    const int dst = lbase[cell] + atomicAdd(&wp[cell], 1);
    cb[dst] = make_float4(x, y, z, __int_as_float(p));

    const int tile = dst >> 7;      // dst / TILE
    atomicMax(&au[tile * 6 + 0], ~keyf(x));   // min slots: max of ~key
    atomicMax(&au[tile * 6 + 1], ~keyf(y));
    atomicMax(&au[tile * 6 + 2], ~keyf(z));
    atomicMax(&au[tile * 6 + 3], keyf(x));    // max slots: max of key
    atomicMax(&au[tile * 6 + 4], keyf(y));
    atomicMax(&au[tile * 6 + 5], keyf(z));
}

// Frozen distance chain for candidate C vs query q (do not reorder).
#define DIST_TO(C, q, dout)                                                 \
  { const float csq_ = __fmaf_rn((C).z, (C).z, __fmaf_rn((C).y, (C).y,      \
                                 __fmul_rn((C).x, (C).x)));                 \
    float dot_ = __fmul_rn((C).x, qx[q]);                                   \
    dot_ = __fmaf_rn((C).y, qy[q], dot_);                                   \
    dot_ = __fmaf_rn((C).z, qz[q], dot_);                                   \
    (dout) = __fmaf_rn(dot_, -2.0f, __fadd_rn(qsq[q], csq_)); }

// One 64-candidate batch vs the wave's 4 queries (proven in R8/R9).
#define PROCESS_BATCH(C)                                                    \
  {                                                                         \
    const float cx = (C).x, cy = (C).y, cz = (C).z;                         \
    const int corig = __float_as_int((C).w);                                \
    const float csq = __fmaf_rn(cz, cz, __fmaf_rn(cy, cy,                   \
                                __fmul_rn(cx, cx)));                        \
    _Pragma("unroll")                                                       \
    for (int q = 0; q < WQ; ++q) {                                          \
      float dot = __fmul_rn(cx, qx[q]);                                     \
      dot = __fmaf_rn(cy, qy[q], dot);                                      \
      dot = __fmaf_rn(cz, qz[q], dot);                                      \
      const float sum = __fadd_rn(qsq[q], csq);                             \
      const float d = __fmaf_rn(dot, -2.0f, sum);                           \
      unsigned long long m = __ballot(d <= worst[q]);                       \
      while (m) {                                                           \
        const int sl = (int)__builtin_ctzll(m);                             \
        m &= m - 1;                                                         \
        const float nd = __int_as_float(__builtin_amdgcn_readlane(          \
            __float_as_int(d), sl));                                        \
        if (nd <= worst[q]) {                                               \
          const int norig = __builtin_amdgcn_readlane(corig, sl);           \
          const float pld = __int_as_float(                                 \
              __builtin_amdgcn_ds_bpermute(upaddr, __float_as_int(ld)));    \
          const int pli = __builtin_amdgcn_ds_bpermute(upaddr, li);         \
          const bool gt = (ld > nd) || (ld == nd && li > norig);            \
          if (ingrp[q] && gt) {                                             \
            const bool pgt = (pld > nd) || (pld == nd && pli > norig);      \
            const bool fst = (lrank == 0) || (!pgt);                        \
            ld = fst ? nd : pld;                                            \
            li = fst ? norig : pli;                                         \
          }                                                                 \
          worst[q] = fminf(worst[q],                                        \
              __int_as_float(__builtin_amdgcn_readlane(                     \
                  __float_as_int(ld), q * 16 + (KK - 1))));                 \
        }                                                                   \
      }                                                                     \
    }                                                                       \
  }

#define WMAX4 fmaxf(fmaxf(worst[0], worst[1]), fmaxf(worst[2], worst[3]))

__global__ __launch_bounds__(NTHREADS) void knn_pool_kernel(
    const float* __restrict__ src_f, const float* __restrict__ tgt_f,
    const float4* __restrict__ cand, const unsigned* __restrict__ aabbu,
    float* __restrict__ out)
{
    const int inst = blockIdx.x & 1;
    const float* __restrict__ feats = inst ? tgt_f : src_f;
    float* __restrict__ outb = out + (size_t)inst * N_PTS * (2 * C_FEAT);
    const float4* __restrict__ cd = cand + inst * N_PTS;

    const int tid = threadIdx.x, wave = tid >> 6, lane = tid & 63;
    const int lq = lane >> 4, lrank = lane & 15;
    const bool inlist = (lrank < KK);
    const int upaddr = ((lane + 63) & 63) << 2;   // ds_bpermute: lane-1

    __shared__ float sab[NTILES * 6];                 // 3 KB
    __shared__ unsigned int slist[NWAVES][NTILES];    // packed (lb|tile), 2 KB
    for (int i = tid; i < NTILES * 6; i += NTHREADS) {
        const unsigned u = aabbu[inst * NTILES * 6 + i];
        sab[i] = unkeyf((i % 6) < 3 ? ~u : u);
    }
    __syncthreads();

    const int q0 = (blockIdx.x >> 1) * QPB + wave * WQ;  // sorted row
    float qx[WQ], qy[WQ], qz[WQ], qsq[WQ];
    int qor[WQ]; bool ingrp[WQ]; float worst[WQ];
    float wqmnx = FLT_MAX, wqmny = FLT_MAX, wqmnz = FLT_MAX;
    float wqmxx = -FLT_MAX, wqmxy = -FLT_MAX, wqmxz = -FLT_MAX;
    #pragma unroll
    for (int q = 0; q < WQ; ++q) {
        const float4 c = cd[q0 + q];
        qx[q] = c.x; qy[q] = c.y; qz[q] = c.z;
        qor[q] = __float_as_int(c.w);
        qsq[q] = __fmaf_rn(c.z, c.z, __fmaf_rn(c.y, c.y, __fmul_rn(c.x, c.x)));
        ingrp[q] = inlist && (lq == q);
        worst[q] = FLT_MAX;
        wqmnx = fminf(wqmnx, c.x); wqmxx = fmaxf(wqmxx, c.x);
        wqmny = fminf(wqmny, c.y); wqmxy = fmaxf(wqmxy, c.y);
        wqmnz = fminf(wqmnz, c.z); wqmxz = fmaxf(wqmxz, c.z);
    }

    float ld = FLT_MAX;   // lane-distributed sorted list (lex (d, orig_idx))
    int   li = 0x7fffffff;

    const int ownt = q0 / TILE;   // tile containing the queries

    // ---- own tile: radix-select exact 11th distance -> tight worst init --
    {
        const float4 c0 = cd[ownt * TILE + lane];
        const float4 c1 = cd[ownt * TILE + 64 + lane];

        // Order-preserving uint keys of the frozen fp32 distances
        // (bijective; handles the -eps self-distance sign case).
        unsigned k0[WQ], k1[WQ], pk[WQ];
        #pragma unroll
        for (int q = 0; q < WQ; ++q) {
            float d0, d1;
            DIST_TO(c0, q, d0);
            DIST_TO(c1, q, d1);
            const unsigned b0 = __float_as_uint(d0), b1 = __float_as_uint(d1);
            k0[q] = b0 ^ (((unsigned)((int)b0 >> 31)) | 0x80000000u);
            k1[q] = b1 ^ (((unsigned)((int)b1 >> 31)) | 0x80000000u);
            pk[q] = 0u;
        }
        // MSB->LSB bisection: after the loop pk[q] == key of the exact
        // 11th-smallest (counting multiplicity) of the 128 own-tile dists.
        for (int b = 31; b >= 0; --b) {
            #pragma unroll
            for (int q = 0; q < WQ; ++q) {
                const unsigned mid = pk[q] | (1u << b);
                const int cnt = (int)__popcll(__ballot(k0[q] < mid))
                              + (int)__popcll(__ballot(k1[q] < mid));
                if (cnt < KK) pk[q] = mid;
            }
        }
        #pragma unroll
        for (int q = 0; q < WQ; ++q) {
            const unsigned p = pk[q];
            worst[q] = __uint_as_float(
                (p & 0x80000000u) ? (p ^ 0x80000000u) : ~p);
        }
        // Gated batches: m now has ~11+ties bits total; the serial insert
        // (unchanged logic) rebuilds the exact lex-sorted list.
        PROCESS_BATCH(c0);
        PROCESS_BATCH(c1);
    }
    const float wmax0 = WMAX4;

    // ---- zigzag (near->far) survivor list, built in parallel ----
    // entry = (float_bits(lb) & ~0xFF) | tile  — lb>=0 so uint order == lb
    // order; unpacked lb rounds DOWN => recheck skip stays conservative.
    int nsurv = 0;
    #pragma unroll
    for (int g = 0; g < 4; ++g) {
        const int p = g * 64 + lane;
        const int o = (p >> 1) + 1;
        const int t = (p & 1) ? (ownt - o) : (ownt + o);
        bool ok = (t >= 0) && (t < NTILES);
        float lb = 0.0f;
        if (ok) {
            const float dx = fmaxf(0.f, fmaxf(sab[t*6+0] - wqmxx, wqmnx - sab[t*6+3]));
            const float dy = fmaxf(0.f, fmaxf(sab[t*6+1] - wqmxy, wqmny - sab[t*6+4]));
            const float dz = fmaxf(0.f, fmaxf(sab[t*6+2] - wqmxz, wqmnz - sab[t*6+5]));
            lb = dx * dx;
            lb = fmaf(dy, dy, lb);
            lb = fmaf(dz, dz, lb);
            ok = (lb - 1e-3f) <= wmax0;   // margin >> fp32 chain error
        }
        const unsigned long long mk = __ballot(ok);
        if (ok) {
            const int idx = nsurv + (int)__popcll(mk & ((1ull << lane) - 1ull));
            slist[wave][idx] = (__float_as_uint(lb) & 0xFFFFFF00u) | (unsigned)t;
        }
        nsurv += (int)__popcll(mk);
    }

    // ---- scan survivors: 4-slot prefetch ring + LIVE recheck vs wmax ----
    // Loads for slot s issue while slot s-4 is processed (~3 tiles of
    // latency cover for the occupancy-decayed tail regime). Tail slots
    // prefetch ownt harmlessly (never processed: loop bound).
    float4 T0a, T0b, T1a, T1b, T2a, T2b, T3a, T3b;
    unsigned int u0 = 0, u1 = 0, u2 = 0, u3 = 0;
    {
        u0 = (0 < nsurv) ? slist[wave][0] : (unsigned)ownt;
        const int t0 = (int)(u0 & 0xFFu);
        T0a = cd[t0 * TILE + lane]; T0b = cd[t0 * TILE + 64 + lane];
        u1 = (1 < nsurv) ? slist[wave][1] : (unsigned)ownt;
        const int t1 = (int)(u1 & 0xFFu);
        T1a = cd[t1 * TILE + lane]; T1b = cd[t1 * TILE + 64 + lane];
        u2 = (2 < nsurv) ? slist[wave][2] : (unsigned)ownt;
        const int t2 = (int)(u2 & 0xFFu);
        T2a = cd[t2 * TILE + lane]; T2b = cd[t2 * TILE + 64 + lane];
        u3 = (3 < nsurv) ? slist[wave][3] : (unsigned)ownt;
        const int t3 = (int)(u3 & 0xFFu);
        T3a = cd[t3 * TILE + lane]; T3b = cd[t3 * TILE + 64 + lane];
    }
    #define SCAN_STEP(UA, TA, TB)                                           \
      {                                                                     \
        const unsigned uN = (s + 4 < nsurv) ? slist[wave][s + 4]            \
                                            : (unsigned)ownt;               \
        const int tn = (int)(uN & 0xFFu);                                   \
        if (__uint_as_float(UA & 0xFFFFFF00u) - 1e-3f <= WMAX4) {           \
            PROCESS_BATCH(TA);                                              \
            PROCESS_BATCH(TB);                                              \
        }                                                                   \
        UA = uN;                                                            \
        TA = cd[tn * TILE + lane]; TB = cd[tn * TILE + 64 + lane];          \
        ++s;                                                                \
      }
    int s = 0;
    while (s < nsurv) {
        SCAN_STEP(u0, T0a, T0b);
        if (s >= nsurv) break;
        SCAN_STEP(u1, T1a, T1b);
        if (s >= nsurv) break;
        SCAN_STEP(u2, T2a, T2b);
        if (s >= nsurv) break;
        SCAN_STEP(u3, T3a, T3b);
    }
    #undef SCAN_STEP

    // Rank 0 (lex-smallest: self or -1ulp near-twin) dropped positionally.
    // Ranks 1..10 -> feature columns 0..9. li holds ORIGINAL indices.
    float fv = -FLT_MAX;
    if (inlist && lrank >= 1)
        fv = feats[(size_t)li * C_FEAT + (lrank - 1)];
    #pragma unroll
    for (int off = 1; off < 16; off <<= 1)
        fv = fmaxf(fv, __shfl_xor(fv, off));

    #pragma unroll
    for (int q = 0; q < WQ; ++q) {
        const float M   = __shfl(fv, q * 16);
        const int   row = qor[q];
        const float v   = feats[(size_t)row * C_FEAT + lane];
        outb[(size_t)row * (2 * C_FEAT) + lane]          = v;
        outb[(size_t)row * (2 * C_FEAT) + C_FEAT + lane] = M - v;
    }
}

extern "C" void kernel_launch(void* const* d_in, const int* in_sizes, int n_in,
                              void* d_out, int out_size, void* d_ws, size_t ws_size,
                              hipStream_t stream) {
    const float* src_f = (const float*)d_in[0];
    const float* tgt_f = (const float*)d_in[1];
    const float* src_c = (const float*)d_in[2];
    const float* tgt_c = (const float*)d_in[3];
    float* out = (float*)d_out;

    char* ws = (char*)d_ws;
    float4*   cand  = (float4*)  (ws + WS_CAND);
    unsigned* aabbu = (unsigned*)(ws + WS_AABBU);
    int*      hist  = (int*)     (ws + WS_HIST);
    int*      wptr  = (int*)     (ws + WS_WPTR);

    // Zero aabbu + hist + wptr in one contiguous memset.
    hipMemsetAsync(aabbu, 0, WS_ZERO_BYTES, stream);
    hipLaunchKernelGGL(hist_kernel, dim3(128), dim3(256), 0, stream,
                       src_c, tgt_c, hist);
    hipLaunchKernelGGL(scanscatter_kernel, dim3(128), dim3(256), 0, stream,
                       src_c, tgt_c, hist, wptr, aabbu, cand);
    hipLaunchKernelGGL(knn_pool_kernel, dim3(2 * (N_PTS / QPB)), dim3(NTHREADS),
                       0, stream, src_f, tgt_f, cand, aabbu, out);
}

// Round 9
// 210.312 us; speedup vs baseline: 1.1793x; 1.0482x over previous
//
#include <hip/hip_runtime.h>
#include <cfloat>
#include <math.h>

// Exact-replication KNN (k=10, +self) + rank-column gather max-pool.
// NUMERICS FROZEN (R3 pass, absmax 0.0): fp32 chains
//   sq  = fma(z,z, fma(y,y, rn(x*x)))
//   dot = fma(z,z', fma(y,y', rn(x*x')))
//   d   = fma(dot, -2, rn(sq_i+sq_j))    [== rn(sum - rn(2*dot)), 2*dot exact]
// Selection order = jax top_k = ascending lexicographic (d, orig_idx) —
// proven order-independent in R8/R9 (absmax 0.0, nondeterministic scatter).
//
// Round 19: R17/R18 post-mortem — the ~75 us wall-minus-knn gap is FIXED
// harness overhead (R10 3-dispatch and R11 6-dispatch had the same gap;
// both fusion attempts regressed via barrier-spin / atomic contention).
// Prepass reverted to the R11/R16 form and frozen. Only lever: knn kernel.
// New: INTERLEAVED INSERT CHAINS. The 4 queries' serial insertion loops are
// data-independent, but shared ld/li registers serialized them at the
// register level. Now each query owns its list registers (ld0..3/li0..3)
// and a merged loop processes one candidate from each non-empty mask per
// iteration -> 4 independent ~200cy readlane/bpermute chains overlap.
// Same per-query ctz order + live recheck -> bit-identical selection.

#define N_PTS    16384
#define C_FEAT   64
#define KK       11
#define NCELLS   4096                 // 16^3 Morton cells
#define TILE     128                  // sorted points per tile
#define NTILES   (N_PTS / TILE)       // 128
#define WQ       4
#define NWAVES   4
#define NTHREADS (NWAVES * 64)
#define QPB      (NWAVES * WQ)        // 16 queries per block

// d_ws layout (bytes)
#define WS_CAND  0                            // float4[2][N_PTS]   512 KB
#define WS_AABB  (WS_CAND + 2*N_PTS*16)       // float[2][NTILES][6]  6 KB
#define WS_HIST  (WS_AABB + 2*NTILES*6*4)     // int[2][NCELLS]      32 KB

__device__ __forceinline__ int cell_of(float x, float y, float z) {
    int cx = (int)floorf((x + 4.5f) * (16.0f / 9.0f));
    int cy = (int)floorf((y + 4.5f) * (16.0f / 9.0f));
    int cz = (int)floorf((z + 4.5f) * (16.0f / 9.0f));
    cx = min(15, max(0, cx));
    cy = min(15, max(0, cy));
    cz = min(15, max(0, cz));
    int m = 0;
    #pragma unroll
    for (int b = 0; b < 4; ++b)
        m |= (((cx >> b) & 1) << (3 * b)) |
             (((cy >> b) & 1) << (3 * b + 1)) |
             (((cz >> b) & 1) << (3 * b + 2));
    return m;
}

// 128 blocks x 256 thr, one point per thread. Global atomics into hist
// (pre-zeroed by hipMemsetAsync).
__global__ __launch_bounds__(256) void hist_kernel(
    const float* __restrict__ src_c, const float* __restrict__ tgt_c,
    int* __restrict__ hist)
{
    const int inst = blockIdx.x >> 6;           // 64 blocks per instance
    const float* __restrict__ coords = inst ? tgt_c : src_c;
    int* __restrict__ h = hist + inst * NCELLS;
    const int p = ((blockIdx.x & 63) << 8) + threadIdx.x;
    const float* c = coords + (size_t)p * 3;
    atomicAdd(&h[cell_of(c[0], c[1], c[2])], 1);
}

// One block per instance. Barrier scan; leaves h[cell] = exclusive base.
__global__ __launch_bounds__(1024) void scan_kernel(int* __restrict__ hist)
{
    const int inst = blockIdx.x;
    int* __restrict__ h = hist + inst * NCELLS;
    __shared__ int sd[1024];
    const int t = threadIdx.x;

    int v[4], ssum = 0;
    #pragma unroll
    for (int j = 0; j < 4; ++j) { v[j] = h[t * 4 + j]; ssum += v[j]; }
    sd[t] = ssum;
    __syncthreads();
    for (int off = 1; off < 1024; off <<= 1) {
        const int x = (t >= off) ? sd[t - off] : 0;
        __syncthreads();
        sd[t] += x;
        __syncthreads();
    }
    int base = sd[t] - ssum;
    #pragma unroll
    for (int j = 0; j < 4; ++j) { h[t * 4 + j] = base; base += v[j]; }
}

// 128 blocks x 256 thr. dst = atomicAdd(write-pointer). Within-cell order is
// nondeterministic — exactly as R8-R18 (selection proven order-independent).
__global__ __launch_bounds__(256) void scatter_kernel(
    const float* __restrict__ src_c, const float* __restrict__ tgt_c,
    int* __restrict__ hist, float4* __restrict__ cand)
{
    const int inst = blockIdx.x >> 6;
    const float* __restrict__ coords = inst ? tgt_c : src_c;
    int* __restrict__ h = hist + inst * NCELLS;
    float4* __restrict__ cb = cand + inst * N_PTS;
    const int p = ((blockIdx.x & 63) << 8) + threadIdx.x;
    const float* c = coords + (size_t)p * 3;
    const float x = c[0], y = c[1], z = c[2];
    const int dst = atomicAdd(&h[cell_of(x, y, z)], 1);
    cb[dst] = make_float4(x, y, z, __int_as_float(p));
}

__global__ void aabb_kernel(const float4* __restrict__ cand,
                            float* __restrict__ aabb) {
    const int it = blockIdx.x;                 // inst*NTILES + tile
    const int base = (it / NTILES) * N_PTS + (it % NTILES) * TILE;
    const int lane = threadIdx.x;              // 64 threads, 2 pts each
    float4 a = cand[base + lane], b = cand[base + 64 + lane];
    float mnx = fminf(a.x, b.x), mny = fminf(a.y, b.y), mnz = fminf(a.z, b.z);
    float mxx = fmaxf(a.x, b.x), mxy = fmaxf(a.y, b.y), mxz = fmaxf(a.z, b.z);
    #pragma unroll
    for (int off = 1; off < 64; off <<= 1) {
        mnx = fminf(mnx, __shfl_xor(mnx, off));
        mny = fminf(mny, __shfl_xor(mny, off));
        mnz = fminf(mnz, __shfl_xor(mnz, off));
        mxx = fmaxf(mxx, __shfl_xor(mxx, off));
        mxy = fmaxf(mxy, __shfl_xor(mxy, off));
        mxz = fmaxf(mxz, __shfl_xor(mxz, off));
    }
    if (lane == 0) {
        aabb[it * 6 + 0] = mnx; aabb[it * 6 + 1] = mny; aabb[it * 6 + 2] = mnz;
        aabb[it * 6 + 3] = mxx; aabb[it * 6 + 4] = mxy; aabb[it * 6 + 5] = mxz;
    }
}

// Frozen distance chain for candidate C vs query q (do not reorder).
#define DIST_TO(C, q, dout)                                                 \
  { const float csq_ = __fmaf_rn((C).z, (C).z, __fmaf_rn((C).y, (C).y,      \
                                 __fmul_rn((C).x, (C).x)));                 \
    float dot_ = __fmul_rn((C).x, qx[q]);                                   \
    dot_ = __fmaf_rn((C).y, qy[q], dot_);                                   \
    dot_ = __fmaf_rn((C).z, qz[q], dot_);                                   \
    (dout) = __fmaf_rn(dot_, -2.0f, __fadd_rn(qsq[q], csq_)); }

// One insert step for query q: consume one candidate from mask M in ctz
// order with live recheck. Identical semantics to R14-R16; LD/LI are this
// query's private list registers (chain independence across queries).
#define INS_STEP(q, M, D, LD, LI)                                           \
    if (M) {                                                                \
      const int sl = (int)__builtin_ctzll(M);                               \
      M &= M - 1;                                                           \
      const float nd = __int_as_float(__builtin_amdgcn_readlane(            \
          __float_as_int(D), sl));                                          \
      if (nd <= worst[q]) {                                                 \
        const int norig = __builtin_amdgcn_readlane(corig, sl);             \
        const float pld = __int_as_float(                                   \
            __builtin_amdgcn_ds_bpermute(upaddr, __float_as_int(LD)));      \
        const int pli = __builtin_amdgcn_ds_bpermute(upaddr, LI);           \
        const bool gt = (LD > nd) || (LD == nd && LI > norig);              \
        if (ingrp[q] && gt) {                                               \
          const bool pgt = (pld > nd) || (pld == nd && pli > norig);        \
          const bool fst = (lrank == 0) || (!pgt);                          \
          LD = fst ? nd : pld;                                              \
          LI = fst ? norig : pli;                                           \
        }                                                                   \
        worst[q] = fminf(worst[q],                                          \
            __int_as_float(__builtin_amdgcn_readlane(                       \
                __float_as_int(LD), q * 16 + (KK - 1))));                   \
      }                                                                     \
    }

// One 64-candidate batch vs the wave's 4 queries. Distances for all 4
// queries first, then a merged loop draining the 4 masks round-robin so
// the 4 independent readlane/bpermute chains overlap.
#define PROCESS_BATCH(C)                                                    \
  {                                                                         \
    const float cx = (C).x, cy = (C).y, cz = (C).z;                         \
    const int corig = __float_as_int((C).w);                                \
    const float csq = __fmaf_rn(cz, cz, __fmaf_rn(cy, cy,                   \
                                __fmul_rn(cx, cx)));                        \
    float d0, d1, d2, d3;                                                   \
    { float dt = __fmul_rn(cx, qx[0]); dt = __fmaf_rn(cy, qy[0], dt);       \
      dt = __fmaf_rn(cz, qz[0], dt);                                        \
      d0 = __fmaf_rn(dt, -2.0f, __fadd_rn(qsq[0], csq)); }                  \
    { float dt = __fmul_rn(cx, qx[1]); dt = __fmaf_rn(cy, qy[1], dt);       \
      dt = __fmaf_rn(cz, qz[1], dt);                                        \
      d1 = __fmaf_rn(dt, -2.0f, __fadd_rn(qsq[1], csq)); }                  \
    { float dt = __fmul_rn(cx, qx[2]); dt = __fmaf_rn(cy, qy[2], dt);       \
      dt = __fmaf_rn(cz, qz[2], dt);                                        \
      d2 = __fmaf_rn(dt, -2.0f, __fadd_rn(qsq[2], csq)); }                  \
    { float dt = __fmul_rn(cx, qx[3]); dt = __fmaf_rn(cy, qy[3], dt);       \
      dt = __fmaf_rn(cz, qz[3], dt);                                        \
      d3 = __fmaf_rn(dt, -2.0f, __fadd_rn(qsq[3], csq)); }                  \
    unsigned long long m0 = __ballot(d0 <= worst[0]);                       \
    unsigned long long m1 = __ballot(d1 <= worst[1]);                       \
    unsigned long long m2 = __ballot(d2 <= worst[2]);                       \
    unsigned long long m3 = __ballot(d3 <= worst[3]);                       \
    while (m0 | m1 | m2 | m3) {                                             \
      INS_STEP(0, m0, d0, ld0, li0)                                         \
      INS_STEP(1, m1, d1, ld1, li1)                                         \
      INS_STEP(2, m2, d2, ld2, li2)                                         \
      INS_STEP(3, m3, d3, ld3, li3)                                         \
    }                                                                       \
  }

#define WMAX4 fmaxf(fmaxf(worst[0], worst[1]), fmaxf(worst[2], worst[3]))

__global__ __launch_bounds__(NTHREADS) void knn_pool_kernel(
    const float* __restrict__ src_f, const float* __restrict__ tgt_f,
    const float4* __restrict__ cand, const float* __restrict__ aabb,
    float* __restrict__ out)
{
    const int inst = blockIdx.x & 1;
    const float* __restrict__ feats = inst ? tgt_f : src_f;
    float* __restrict__ outb = out + (size_t)inst * N_PTS * (2 * C_FEAT);
    const float4* __restrict__ cd = cand + inst * N_PTS;

    const int tid = threadIdx.x, wave = tid >> 6, lane = tid & 63;
    const int lq = lane >> 4, lrank = lane & 15;
    const bool inlist = (lrank < KK);
    const int upaddr = ((lane + 63) & 63) << 2;   // ds_bpermute: lane-1

    __shared__ float sab[NTILES * 6];                 // 3 KB
    __shared__ unsigned int slist[NWAVES][NTILES];    // packed (lb|tile), 2 KB
    for (int i = tid; i < NTILES * 6; i += NTHREADS)
        sab[i] = aabb[inst * NTILES * 6 + i];
    __syncthreads();

    const int q0 = (blockIdx.x >> 1) * QPB + wave * WQ;  // sorted row
    float qx[WQ], qy[WQ], qz[WQ], qsq[WQ];
    int qor[WQ]; bool ingrp[WQ]; float worst[WQ];
    float wqmnx = FLT_MAX, wqmny = FLT_MAX, wqmnz = FLT_MAX;
    float wqmxx = -FLT_MAX, wqmxy = -FLT_MAX, wqmxz = -FLT_MAX;
    #pragma unroll
    for (int q = 0; q < WQ; ++q) {
        const float4 c = cd[q0 + q];
        qx[q] = c.x; qy[q] = c.y; qz[q] = c.z;
        qor[q] = __float_as_int(c.w);
        qsq[q] = __fmaf_rn(c.z, c.z, __fmaf_rn(c.y, c.y, __fmul_rn(c.x, c.x)));
        ingrp[q] = inlist && (lq == q);
        worst[q] = FLT_MAX;
        wqmnx = fminf(wqmnx, c.x); wqmxx = fmaxf(wqmxx, c.x);
        wqmny = fminf(wqmny, c.y); wqmxy = fmaxf(wqmxy, c.y);
        wqmnz = fminf(wqmnz, c.z); wqmxz = fmaxf(wqmxz, c.z);
    }

    // Per-query lane-distributed sorted lists (lex (d, orig_idx)).
    float ld0 = FLT_MAX, ld1 = FLT_MAX, ld2 = FLT_MAX, ld3 = FLT_MAX;
    int   li0 = 0x7fffffff, li1 = 0x7fffffff;
    int   li2 = 0x7fffffff, li3 = 0x7fffffff;

    const int ownt = q0 / TILE;   // tile containing the queries

    // ---- own tile: radix-select exact 11th distance -> tight worst init --
    {
        const float4 c0 = cd[ownt * TILE + lane];
        const float4 c1 = cd[ownt * TILE + 64 + lane];

        // Order-preserving uint keys of the frozen fp32 distances
        // (bijective; handles the -eps self-distance sign case).
        unsigned k0[WQ], k1[WQ], pk[WQ];
        #pragma unroll
        for (int q = 0; q < WQ; ++q) {
            float da, db;
            DIST_TO(c0, q, da);
            DIST_TO(c1, q, db);
            const unsigned b0 = __float_as_uint(da), b1 = __float_as_uint(db);
            k0[q] = b0 ^ (((unsigned)((int)b0 >> 31)) | 0x80000000u);
            k1[q] = b1 ^ (((unsigned)((int)b1 >> 31)) | 0x80000000u);
            pk[q] = 0u;
        }
        // MSB->LSB bisection: after the loop pk[q] == key of the exact
        // 11th-smallest (counting multiplicity) of the 128 own-tile dists.
        for (int b = 31; b >= 0; --b) {
            #pragma unroll
            for (int q = 0; q < WQ; ++q) {
                const unsigned mid = pk[q] | (1u << b);
                const int cnt = (int)__popcll(__ballot(k0[q] < mid))
                              + (int)__popcll(__ballot(k1[q] < mid));
                if (cnt < KK) pk[q] = mid;
            }
        }
        #pragma unroll
        for (int q = 0; q < WQ; ++q) {
            const unsigned p = pk[q];
            worst[q] = __uint_as_float(
                (p & 0x80000000u) ? (p ^ 0x80000000u) : ~p);
        }
        // Gated batches: ~11+ties candidates per query enter the merged
        // insert loop; chains for the 4 queries overlap.
        PROCESS_BATCH(c0);
        PROCESS_BATCH(c1);
    }
    const float wmax0 = WMAX4;

    // ---- zigzag (near->far) survivor list, built in parallel ----
    // entry = (float_bits(lb) & ~0xFF) | tile  — lb>=0 so uint order == lb
    // order; unpacked lb rounds DOWN => recheck skip stays conservative.
    int nsurv = 0;
    #pragma unroll
    for (int g = 0; g < 4; ++g) {
        const int p = g * 64 + lane;
        const int o = (p >> 1) + 1;
        const int t = (p & 1) ? (ownt - o) : (ownt + o);
        bool ok = (t >= 0) && (t < NTILES);
        float lb = 0.0f;
        if (ok) {
            const float dx = fmaxf(0.f, fmaxf(sab[t*6+0] - wqmxx, wqmnx - sab[t*6+3]));
            const float dy = fmaxf(0.f, fmaxf(sab[t*6+1] - wqmxy, wqmny - sab[t*6+4]));
            const float dz = fmaxf(0.f, fmaxf(sab[t*6+2] - wqmxz, wqmnz - sab[t*6+5]));
            lb = dx * dx;
            lb = fmaf(dy, dy, lb);
            lb = fmaf(dz, dz, lb);
            ok = (lb - 1e-3f) <= wmax0;   // margin >> fp32 chain error
        }
        const unsigned long long mk = __ballot(ok);
        if (ok) {
            const int idx = nsurv + (int)__popcll(mk & ((1ull << lane) - 1ull));
            slist[wave][idx] = (__float_as_uint(lb) & 0xFFFFFF00u) | (unsigned)t;
        }
        nsurv += (int)__popcll(mk);
    }

    // ---- scan survivors: 4-slot prefetch ring + LIVE recheck vs wmax ----
    // Loads for slot s issue while slot s-4 is processed (~3 tiles of
    // latency cover for the occupancy-decayed tail regime). Tail slots
    // prefetch ownt harmlessly (never processed: loop bound).
    float4 T0a, T0b, T1a, T1b, T2a, T2b, T3a, T3b;
    unsigned int u0 = 0, u1 = 0, u2 = 0, u3 = 0;
    {
        u0 = (0 < nsurv) ? slist[wave][0] : (unsigned)ownt;
        const int t0 = (int)(u0 & 0xFFu);
        T0a = cd[t0 * TILE + lane]; T0b = cd[t0 * TILE + 64 + lane];
        u1 = (1 < nsurv) ? slist[wave][1] : (unsigned)ownt;
        const int t1 = (int)(u1 & 0xFFu);
        T1a = cd[t1 * TILE + lane]; T1b = cd[t1 * TILE + 64 + lane];
        u2 = (2 < nsurv) ? slist[wave][2] : (unsigned)ownt;
        const int t2 = (int)(u2 & 0xFFu);
        T2a = cd[t2 * TILE + lane]; T2b = cd[t2 * TILE + 64 + lane];
        u3 = (3 < nsurv) ? slist[wave][3] : (unsigned)ownt;
        const int t3 = (int)(u3 & 0xFFu);
        T3a = cd[t3 * TILE + lane]; T3b = cd[t3 * TILE + 64 + lane];
    }
    #define SCAN_STEP(UA, TA, TB)                                           \
      {                                                                     \
        const unsigned uN = (s + 4 < nsurv) ? slist[wave][s + 4]            \
                                            : (unsigned)ownt;               \
        const int tn = (int)(uN & 0xFFu);                                   \
        if (__uint_as_float(UA & 0xFFFFFF00u) - 1e-3f <= WMAX4) {           \
            PROCESS_BATCH(TA);                                              \
            PROCESS_BATCH(TB);                                              \
        }                                                                   \
        UA = uN;                                                            \
        TA = cd[tn * TILE + lane]; TB = cd[tn * TILE + 64 + lane];          \
        ++s;                                                                \
      }
    int s = 0;
    while (s < nsurv) {
        SCAN_STEP(u0, T0a, T0b);
        if (s >= nsurv) break;
        SCAN_STEP(u1, T1a, T1b);
        if (s >= nsurv) break;
        SCAN_STEP(u2, T2a, T2b);
        if (s >= nsurv) break;
        SCAN_STEP(u3, T3a, T3b);
    }
    #undef SCAN_STEP

    // Merge per-query list registers by lane group for the output gather.
    const int lim = (lq == 0) ? li0 : (lq == 1) ? li1 : (lq == 2) ? li2 : li3;

    // Rank 0 (lex-smallest: self or -1ulp near-twin) dropped positionally.
    // Ranks 1..10 -> feature columns 0..9. lim holds ORIGINAL indices.
    float fv = -FLT_MAX;
    if (inlist && lrank >= 1)
        fv = feats[(size_t)lim * C_FEAT + (lrank - 1)];
    #pragma unroll
    for (int off = 1; off < 16; off <<= 1)
        fv = fmaxf(fv, __shfl_xor(fv, off));

    #pragma unroll
    for (int q = 0; q < WQ; ++q) {
        const float M   = __shfl(fv, q * 16);
        const int   row = qor[q];
        const float v   = feats[(size_t)row * C_FEAT + lane];
        outb[(size_t)row * (2 * C_FEAT) + lane]          = v;
        outb[(size_t)row * (2 * C_FEAT) + C_FEAT + lane] = M - v;
    }
}

extern "C" void kernel_launch(void* const* d_in, const int* in_sizes, int n_in,
                              void* d_out, int out_size, void* d_ws, size_t ws_size,
                              hipStream_t stream) {
    const float* src_f = (const float*)d_in[0];
    const float* tgt_f = (const float*)d_in[1];
    const float* src_c = (const float*)d_in[2];
    const float* tgt_c = (const float*)d_in[3];
    float* out = (float*)d_out;

    char* ws = (char*)d_ws;
    float4* cand = (float4*)(ws + WS_CAND);
    float*  aabb = (float*) (ws + WS_AABB);
    int*    hist = (int*)   (ws + WS_HIST);

    hipMemsetAsync(hist, 0, 2 * NCELLS * sizeof(int), stream);
    hipLaunchKernelGGL(hist_kernel, dim3(128), dim3(256), 0, stream,
                       src_c, tgt_c, hist);
    hipLaunchKernelGGL(scan_kernel, dim3(2), dim3(1024), 0, stream, hist);
    hipLaunchKernelGGL(scatter_kernel, dim3(128), dim3(256), 0, stream,
                       src_c, tgt_c, hist, cand);
    hipLaunchKernelGGL(aabb_kernel, dim3(2 * NTILES), dim3(64), 0, stream,
                       cand, aabb);
    hipLaunchKernelGGL(knn_pool_kernel, dim3(2 * (N_PTS / QPB)), dim3(NTHREADS),
                       0, stream, src_f, tgt_f, cand, aabb, out);
}